// Round 5
// baseline (157.965 us; speedup 1.0000x reference)
//
#include <hip/hip_runtime.h>

// VQ-VAE VectorQuantizer for MI355X.
// inputs: d_in[0] = inputs [64, 64, 32, 32] fp32 (NCHW), d_in[1] = emb_w [512, 64] fp32
// output d_out (fp32): [loss(1), quantized NCHW (64*64*32*32), idx (65536)]
//
// Correctness (bit-replication of the fp32 reference; DO NOT reorder):
//   norms: numpy pairwise order (8 accs, tree combine)
//   dot:   sequential FMA, d ascending
//   dist:  fmaf(-2, acc, add_rn(sx, nk))  [== add_rn(add_rn(sx,nk), -2*acc)]
//   argmin: first index on ties (k ascending in-wave, explicit idx tiebreak in merge)
//
// Perf (R5): x[64] per lane in VGPRs, pinned with empty asm so the compiler
// cannot re-load it from global per k (R4's VGPR=48 showed it did exactly that).
// e-rows come from LDS at a WAVE-UNIFORM address -> ds_read_b128 broadcast
// (1 distinct address = the only LDS pattern measured free). 4 waves split K,
// 1024 blocks = 4 blocks/CU = 4 waves/SIMD; 2 independent k-chains for ILP.

#define D_    64
#define HW_   1024
#define N_    65536
#define K_    512
#define NDTOT 4194304     // 64*64*32*32
#define PB_   64          // points per block (one per lane)

// ||e_k||^2 in numpy pairwise-summation order
__global__ __launch_bounds__(256) void vq_norm_kernel(const float* __restrict__ emb,
                                                      float* __restrict__ wsn) {
    int k = blockIdx.x * 256 + threadIdx.x;
    if (k < K_) {
        const float* e = emb + k * D_;
        float r[8];
#pragma unroll
        for (int j = 0; j < 8; ++j) r[j] = __fmul_rn(e[j], e[j]);
#pragma unroll
        for (int i = 1; i < 8; ++i)
#pragma unroll
            for (int j = 0; j < 8; ++j)
                r[j] = __fadd_rn(r[j], __fmul_rn(e[i * 8 + j], e[i * 8 + j]));
        wsn[k] = __fadd_rn(__fadd_rn(__fadd_rn(r[0], r[1]), __fadd_rn(r[2], r[3])),
                           __fadd_rn(__fadd_rn(r[4], r[5]), __fadd_rn(r[6], r[7])));
    }
}

__global__ __launch_bounds__(256, 4) void vq_main_kernel(const float* __restrict__ inp,
                                                         const float* __restrict__ emb,
                                                         const float* __restrict__ wsn,
                                                         float* __restrict__ out) {
    __shared__ float ldse[128 * D_];   // 32 KB: one 128-code chunk, row-major [k][d]
    __shared__ float ldsn[128];        // chunk norms
    __shared__ float sv[4][PB_];
    __shared__ int   si[4][PB_];
    __shared__ int   fi[PB_];

    const int tid  = threadIdx.x;
    const int lane = tid & 63;
    const int wv   = __builtin_amdgcn_readfirstlane(tid >> 6);  // provably uniform

    const int n0  = blockIdx.x * PB_;
    const int b   = n0 >> 10;
    const int hw0 = n0 & 1023;
    const float* xcol = inp + b * (D_ * HW_) + hw0 + lane;

    // this lane's point in VGPRs; empty asm pins each value so the compiler
    // cannot rematerialize it by re-loading from global inside the k-loop.
    float x[64];
#pragma unroll
    for (int d = 0; d < D_; ++d) {
        float v = xcol[d * HW_];            // wave-coalesced 256B load
        asm volatile("" : "+v"(v));
        x[d] = v;
    }

    // ||x||^2, numpy pairwise order
    float r[8];
#pragma unroll
    for (int j = 0; j < 8; ++j) r[j] = __fmul_rn(x[j], x[j]);
#pragma unroll
    for (int i = 1; i < 8; ++i)
#pragma unroll
        for (int j = 0; j < 8; ++j)
            r[j] = __fadd_rn(r[j], __fmul_rn(x[i * 8 + j], x[i * 8 + j]));
    const float sx = __fadd_rn(__fadd_rn(__fadd_rn(r[0], r[1]), __fadd_rn(r[2], r[3])),
                               __fadd_rn(__fadd_rn(r[4], r[5]), __fadd_rn(r[6], r[7])));

    float runv = 3.4e38f;
    int   runi = 0;

    for (int c = 0; c < 4; ++c) {
        __syncthreads();
        // stage chunk c: 128 codes x 64 d (coalesced float4)
        {
            const float4* src = (const float4*)(emb + c * 128 * D_);
            float4* dst = (float4*)ldse;
#pragma unroll
            for (int i = 0; i < 8; ++i) dst[i * 256 + tid] = src[i * 256 + tid];
            if (tid < 128) ldsn[tid] = wsn[c * 128 + tid];
        }
        __syncthreads();

        // wave wv handles k = c*128 + wv*32 + j, j = 0..31 (pairs for ILP)
        const float* ebase = ldse + wv * 32 * D_;   // uniform
        const int    kbase = c * 128 + wv * 32;
        for (int j = 0; j < 32; j += 2) {
            const float* e0 = ebase + j * D_;       // uniform addr -> broadcast
            const float* e1 = e0 + D_;
            float a0 = 0.f, a1 = 0.f;
#pragma unroll
            for (int d = 0; d < D_; ++d) {          // sequential, d ascending
                a0 = fmaf(x[d], e0[d], a0);
                a1 = fmaf(x[d], e1[d], a1);
            }
            float nk0 = ldsn[wv * 32 + j];
            float nk1 = ldsn[wv * 32 + j + 1];
            float v0 = fmaf(-2.0f, a0, __fadd_rn(sx, nk0));
            float v1 = fmaf(-2.0f, a1, __fadd_rn(sx, nk1));
            if (v0 < runv) { runv = v0; runi = kbase + j; }
            if (v1 < runv) { runv = v1; runi = kbase + j + 1; }
        }
    }

    sv[wv][lane] = runv;
    si[wv][lane] = runi;
    __syncthreads();

    // merge 4 wave-partials; k-sets interleave -> explicit idx tiebreak
    if (tid < PB_) {
        float bv = 3.4e38f; int bi = 0x7fffffff;
#pragma unroll
        for (int g = 0; g < 4; ++g) {
            float v  = sv[g][tid];
            int   ii = si[g][tid];
            if (v < bv || (v == bv && ii < bi)) { bv = v; bi = ii; }
        }
        fi[tid] = bi;
        out[1 + NDTOT + n0 + tid] = (float)bi;   // idx as float
    }
    __syncthreads();

    // quantized output + loss: wave 0 (x already in its registers)
    if (wv == 0) {
        const int idx = fi[lane];
        const float4* erow = (const float4*)(emb + idx * D_);  // L2-hot gather
        float* ob = out + 1 + b * (D_ * HW_) + hw0 + lane;     // coalesced stores
        float local = 0.f;
#pragma unroll
        for (int j = 0; j < 16; ++j) {
            float4 e4 = erow[j];
            float ev[4] = {e4.x, e4.y, e4.z, e4.w};
#pragma unroll
            for (int cc = 0; cc < 4; ++cc) {
                float df = ev[cc] - x[j * 4 + cc];
                local = fmaf(df, df, local);
                ob[(j * 4 + cc) * HW_] = ev[cc];
            }
        }
#pragma unroll
        for (int off = 32; off > 0; off >>= 1)
            local += __shfl_down(local, off, 64);
        if (lane == 0)
            atomicAdd(out, local * (1.25f / (float)NDTOT));  // 1.25*mean((q-x)^2)
    }
}

extern "C" void kernel_launch(void* const* d_in, const int* in_sizes, int n_in,
                              void* d_out, int out_size, void* d_ws, size_t ws_size,
                              hipStream_t stream) {
    const float* inp = (const float*)d_in[0];
    const float* emb = (const float*)d_in[1];
    float* out = (float*)d_out;
    float* wsn = (float*)d_ws;      // 512 floats: ||e_k||^2

    hipMemsetAsync(d_out, 0, sizeof(float), stream);   // loss accumulator
    vq_norm_kernel<<<2, 256, 0, stream>>>(emb, wsn);
    vq_main_kernel<<<N_ / PB_, 256, 0, stream>>>(inp, emb, wsn, out);
}

// Round 6
// 133.629 us; speedup vs baseline: 1.1821x; 1.1821x over previous
//
#include <hip/hip_runtime.h>

// VQ-VAE VectorQuantizer for MI355X — MFMA screen + exact fp32 rescreen.
// inputs: d_in[0] = inputs [64, 64, 32, 32] fp32 (NCHW), d_in[1] = emb_w [512, 64] fp32
// output d_out (fp32): [loss(1), quantized NCHW (4194304), idx (65536)]
//
// Correctness: reference dist = fl(fl(sx+nk) - 2*dot) in fp32; ties resolved by
// first index. Exact path (verified in R2/R4/R5): numpy-pairwise norms, sequential
// d-ascending FMA dot, v = fmaf(-2,dot,add_rn(sx,nk)), first-index tiebreak.
// MFMA screen: A_k = nk - 2*dot_bf16split; |A_k - (nk-2dot)| <= ~4.5e-5 worst;
// exact argmin k* has A_{k*} <= min_j A_j + 1.05e-4. MARGIN=2e-4 => candidate set
// {A <= m+MARGIN} provably contains k*; all candidates recomputed exactly and
// merged via packed (fp32bits<<32|idx) min => bit-identical to reference argmin.

#define D_     64
#define HW_    1024
#define N_     65536
#define K_     512
#define NDTOT  4194304
#define MARGIN 2e-4f

typedef short v8s __attribute__((ext_vector_type(8)));
typedef float v4f __attribute__((ext_vector_type(4)));

__device__ float g_wsn[K_];            // ||e_k||^2 (exact pairwise order)
__device__ short g_frag[K_ * D_ * 2];  // 128KB bf16 codebook in MFMA B-frag order:
                                       // [(t*4 + s*2 + hl)*64 + lane] x 8 bf16

__device__ __forceinline__ unsigned short bf16rn(float f) {
    unsigned int u = __float_as_uint(f);
    u += 0x7fffu + ((u >> 16) & 1u);
    return (unsigned short)(u >> 16);
}
__device__ __forceinline__ float bf16tof(unsigned short h) {
    return __uint_as_float(((unsigned int)h) << 16);
}

// exact fp32 dist (reference arithmetic) + first-index-tiebreak min via CAS
__device__ __forceinline__ void exact_min(const float* xcolp, const float* __restrict__ emb,
                                          int k, float sx, unsigned long long* keyp) {
    const float* e = emb + k * D_;
    float dot = 0.f;
#pragma unroll 8
    for (int d = 0; d < D_; ++d)
        dot = fmaf(xcolp[d * HW_], e[d], dot);     // sequential, d ascending
    float t1 = __fadd_rn(sx, g_wsn[k]);
    float v  = fmaf(-2.0f, dot, t1);               // == add_rn(t1, -2*dot)
    unsigned long long nv =
        (((unsigned long long)__float_as_uint(v)) << 32) | (unsigned int)k;
    unsigned long long old = *keyp;
    while (nv < old) {
        unsigned long long assumed = old;
        old = atomicCAS(keyp, assumed, nv);
        if (old == assumed) break;
    }
}

// ||e_k||^2 numpy-pairwise; also zeroes the loss accumulator
__global__ __launch_bounds__(256) void vq_prep_norm(const float* __restrict__ emb,
                                                    float* __restrict__ out) {
    int k = blockIdx.x * 256 + threadIdx.x;
    if (k == 0) out[0] = 0.f;
    if (k < K_) {
        const float* e = emb + k * D_;
        float r[8];
#pragma unroll
        for (int j = 0; j < 8; ++j) r[j] = __fmul_rn(e[j], e[j]);
#pragma unroll
        for (int i = 1; i < 8; ++i)
#pragma unroll
            for (int j = 0; j < 8; ++j)
                r[j] = __fadd_rn(r[j], __fmul_rn(e[i * 8 + j], e[i * 8 + j]));
        g_wsn[k] = __fadd_rn(__fadd_rn(__fadd_rn(r[0], r[1]), __fadd_rn(r[2], r[3])),
                             __fadd_rn(__fadd_rn(r[4], r[5]), __fadd_rn(r[6], r[7])));
    }
}

// codebook -> bf16 hi/lo split in fragment order (one thread per 16B frag slot)
__global__ __launch_bounds__(256) void vq_prep_frag(const float* __restrict__ emb) {
    const int t = blockIdx.x;               // code-tile 0..31
    const int tid = threadIdx.x;
    const int s = tid >> 7;                 // kstep
    const int hl = (tid >> 6) & 1;          // hi/lo
    const int lane = tid & 63;
    const int c = lane & 15, q = lane >> 4;
    const float* e = emb + (t * 16 + c) * D_ + s * 32 + q * 8;
    unsigned int u[4];
#pragma unroll
    for (int jp = 0; jp < 4; ++jp) {
        float f0 = e[jp * 2], f1 = e[jp * 2 + 1];
        unsigned short h0, h1;
        if (hl == 0) { h0 = bf16rn(f0); h1 = bf16rn(f1); }
        else {
            h0 = bf16rn(f0 - bf16tof(bf16rn(f0)));
            h1 = bf16rn(f1 - bf16tof(bf16rn(f1)));
        }
        u[jp] = (unsigned int)h0 | ((unsigned int)h1 << 16);
    }
    ((uint4*)g_frag)[(t * 4 + s * 2 + hl) * 64 + lane] =
        make_uint4(u[0], u[1], u[2], u[3]);
}

__global__ __launch_bounds__(256, 2) void vq_main_kernel(const float* __restrict__ inp,
                                                         const float* __restrict__ emb,
                                                         float* __restrict__ out) {
    __shared__ __align__(16) char smem[35344];
    float* ldsx = (float*)smem;                 // phase A: xT[d][128] fp32 (32KB)
    v8s*   ldsB = (v8s*)smem;                   // phase B: frag chunk (32KB)
    float* sxs  = (float*)(smem + 32768);       // ||x_p||^2 [128]
    float* m_   = (float*)(smem + 33280);       // approx min [128]
    int*   ai_  = (int*)(smem + 33792);         // approx argmin / final idx [128]
    unsigned long long* key_ = (unsigned long long*)(smem + 34304);  // [128]
    float* partial = (float*)(smem + 35328);

    const int tid = threadIdx.x;
    const int lane = tid & 63;
    const int w = tid >> 6;
    const int c = lane & 15, q = lane >> 4;

    const int n0 = blockIdx.x * 128;
    const int b = n0 >> 10;
    const int hw0 = n0 & 1023;
    const float* xg = inp + b * (D_ * HW_) + hw0;

    // ---- stage xT[d][p] (coalesced) ----
#pragma unroll
    for (int i = 0; i < 8; ++i) {
        int idx = i * 256 + tid;
        int d = idx >> 5, pq = idx & 31;
        *(float4*)(ldsx + d * 128 + pq * 4) = *(const float4*)(xg + d * HW_ + pq * 4);
    }
    __syncthreads();

    // ---- sxs[p] = ||x_p||^2, numpy pairwise ----
    if (tid < 128) {
        float r[8];
#pragma unroll
        for (int j = 0; j < 8; ++j) { float v = ldsx[j * 128 + tid]; r[j] = __fmul_rn(v, v); }
#pragma unroll
        for (int i = 1; i < 8; ++i)
#pragma unroll
            for (int j = 0; j < 8; ++j) {
                float v = ldsx[(i * 8 + j) * 128 + tid];
                r[j] = __fadd_rn(r[j], __fmul_rn(v, v));
            }
        sxs[tid] = __fadd_rn(__fadd_rn(__fadd_rn(r[0], r[1]), __fadd_rn(r[2], r[3])),
                             __fadd_rn(__fadd_rn(r[4], r[5]), __fadd_rn(r[6], r[7])));
    }

    // ---- A-frags: y = -2x, bf16 hi/lo split; wave w owns points w*32..w*32+31 ----
    v8s ah[2][2], al[2][2];
#pragma unroll
    for (int T = 0; T < 2; ++T)
#pragma unroll
        for (int s = 0; s < 2; ++s) {
            int pt = w * 32 + T * 16 + c;
#pragma unroll
            for (int j = 0; j < 8; ++j) {
                float x = ldsx[(s * 32 + q * 8 + j) * 128 + pt];
                float y = -2.0f * x;                       // exact
                unsigned short yh = bf16rn(y);
                unsigned short yl = bf16rn(y - bf16tof(yh));
                ah[T][s][j] = (short)yh;
                al[T][s][j] = (short)yl;
            }
        }
    __syncthreads();   // ldsx dead from here; ldsB takes over

    float runv[2][4]; int runi[2][4];
#pragma unroll
    for (int T = 0; T < 2; ++T)
#pragma unroll
        for (int r = 0; r < 4; ++r) { runv[T][r] = 3.4e38f; runi[T][r] = 0; }

    // ================= PASS 1: approx min =================
    for (int ch = 0; ch < 4; ++ch) {
        __syncthreads();
        {
            const uint4* src = (const uint4*)(g_frag + ch * 16384);
            uint4* dst = (uint4*)ldsB;
#pragma unroll
            for (int i = 0; i < 8; ++i) dst[i * 256 + tid] = src[i * 256 + tid];
        }
        __syncthreads();
        float nk_arr[8];
#pragma unroll
        for (int ct = 0; ct < 8; ++ct) nk_arr[ct] = g_wsn[ch * 128 + ct * 16 + c];
        for (int ct = 0; ct < 8; ++ct) {
            const int kl = ch * 128 + ct * 16 + c;
            const v8s* bp = ldsB + ct * 256 + lane;    // lane*16B contiguous: conflict-free
            v8s bh0 = bp[0], bl0 = bp[64], bh1 = bp[128], bl1 = bp[192];
            float nk = nk_arr[ct];
            v4f a0 = {nk, nk, nk, nk}, a1 = a0;
            a0 = __builtin_amdgcn_mfma_f32_16x16x32_bf16(ah[0][0], bh0, a0, 0, 0, 0);
            a0 = __builtin_amdgcn_mfma_f32_16x16x32_bf16(ah[0][0], bl0, a0, 0, 0, 0);
            a0 = __builtin_amdgcn_mfma_f32_16x16x32_bf16(al[0][0], bh0, a0, 0, 0, 0);
            a0 = __builtin_amdgcn_mfma_f32_16x16x32_bf16(ah[0][1], bh1, a0, 0, 0, 0);
            a0 = __builtin_amdgcn_mfma_f32_16x16x32_bf16(ah[0][1], bl1, a0, 0, 0, 0);
            a0 = __builtin_amdgcn_mfma_f32_16x16x32_bf16(al[0][1], bh1, a0, 0, 0, 0);
            a1 = __builtin_amdgcn_mfma_f32_16x16x32_bf16(ah[1][0], bh0, a1, 0, 0, 0);
            a1 = __builtin_amdgcn_mfma_f32_16x16x32_bf16(ah[1][0], bl0, a1, 0, 0, 0);
            a1 = __builtin_amdgcn_mfma_f32_16x16x32_bf16(al[1][0], bh0, a1, 0, 0, 0);
            a1 = __builtin_amdgcn_mfma_f32_16x16x32_bf16(ah[1][1], bh1, a1, 0, 0, 0);
            a1 = __builtin_amdgcn_mfma_f32_16x16x32_bf16(ah[1][1], bl1, a1, 0, 0, 0);
            a1 = __builtin_amdgcn_mfma_f32_16x16x32_bf16(al[1][1], bh1, a1, 0, 0, 0);
#pragma unroll
            for (int r = 0; r < 4; ++r) {
                if (a0[r] < runv[0][r]) { runv[0][r] = a0[r]; runi[0][r] = kl; }
                if (a1[r] < runv[1][r]) { runv[1][r] = a1[r]; runi[1][r] = kl; }
            }
        }
    }

    // cross-lane (c=0..15) min per point; deterministic smaller-idx tiebreak
#pragma unroll
    for (int T = 0; T < 2; ++T)
#pragma unroll
        for (int r = 0; r < 4; ++r) {
            float v = runv[T][r]; int i = runi[T][r];
#pragma unroll
            for (int off = 1; off < 16; off <<= 1) {
                float ov = __shfl_xor(v, off, 64);
                int   oi = __shfl_xor(i, off, 64);
                if (ov < v || (ov == v && oi < i)) { v = ov; i = oi; }
            }
            if (c == 0) { int pt = w * 32 + T * 16 + q * 4 + r; m_[pt] = v; ai_[pt] = i; }
        }
    if (tid < 128) key_[tid] = 0xFFFFFFFFFFFFFFFFULL;
    __syncthreads();

    // dense exact pass for each point's approx-argmin
    if (tid < 128) exact_min(xg + tid, emb, ai_[tid], sxs[tid], &key_[tid]);

    float mm[2][4]; int aa[2][4];
#pragma unroll
    for (int T = 0; T < 2; ++T)
#pragma unroll
        for (int r = 0; r < 4; ++r) {
            int pt = w * 32 + T * 16 + q * 4 + r;
            mm[T][r] = m_[pt]; aa[T][r] = ai_[pt];
        }

    // ================= PASS 2: bit-identical re-run, flag candidates =================
    for (int ch = 0; ch < 4; ++ch) {
        __syncthreads();
        {
            const uint4* src = (const uint4*)(g_frag + ch * 16384);
            uint4* dst = (uint4*)ldsB;
#pragma unroll
            for (int i = 0; i < 8; ++i) dst[i * 256 + tid] = src[i * 256 + tid];
        }
        __syncthreads();
        float nk_arr[8];
#pragma unroll
        for (int ct = 0; ct < 8; ++ct) nk_arr[ct] = g_wsn[ch * 128 + ct * 16 + c];
        for (int ct = 0; ct < 8; ++ct) {
            const int kl = ch * 128 + ct * 16 + c;
            const v8s* bp = ldsB + ct * 256 + lane;
            v8s bh0 = bp[0], bl0 = bp[64], bh1 = bp[128], bl1 = bp[192];
            float nk = nk_arr[ct];
            v4f a0 = {nk, nk, nk, nk}, a1 = a0;
            a0 = __builtin_amdgcn_mfma_f32_16x16x32_bf16(ah[0][0], bh0, a0, 0, 0, 0);
            a0 = __builtin_amdgcn_mfma_f32_16x16x32_bf16(ah[0][0], bl0, a0, 0, 0, 0);
            a0 = __builtin_amdgcn_mfma_f32_16x16x32_bf16(al[0][0], bh0, a0, 0, 0, 0);
            a0 = __builtin_amdgcn_mfma_f32_16x16x32_bf16(ah[0][1], bh1, a0, 0, 0, 0);
            a0 = __builtin_amdgcn_mfma_f32_16x16x32_bf16(ah[0][1], bl1, a0, 0, 0, 0);
            a0 = __builtin_amdgcn_mfma_f32_16x16x32_bf16(al[0][1], bh1, a0, 0, 0, 0);
            a1 = __builtin_amdgcn_mfma_f32_16x16x32_bf16(ah[1][0], bh0, a1, 0, 0, 0);
            a1 = __builtin_amdgcn_mfma_f32_16x16x32_bf16(ah[1][0], bl0, a1, 0, 0, 0);
            a1 = __builtin_amdgcn_mfma_f32_16x16x32_bf16(al[1][0], bh0, a1, 0, 0, 0);
            a1 = __builtin_amdgcn_mfma_f32_16x16x32_bf16(ah[1][1], bh1, a1, 0, 0, 0);
            a1 = __builtin_amdgcn_mfma_f32_16x16x32_bf16(ah[1][1], bl1, a1, 0, 0, 0);
            a1 = __builtin_amdgcn_mfma_f32_16x16x32_bf16(al[1][1], bh1, a1, 0, 0, 0);
#pragma unroll
            for (int r = 0; r < 4; ++r) {
                if (a0[r] <= mm[0][r] + MARGIN && kl != aa[0][r]) {
                    int pt = w * 32 + q * 4 + r;
                    exact_min(xg + pt, emb, kl, sxs[pt], &key_[pt]);
                }
                if (a1[r] <= mm[1][r] + MARGIN && kl != aa[1][r]) {
                    int pt = w * 32 + 16 + q * 4 + r;
                    exact_min(xg + pt, emb, kl, sxs[pt], &key_[pt]);
                }
            }
        }
    }
    __syncthreads();

    // ---- idx output ----
    if (tid < 128) {
        unsigned int kf = (unsigned int)(key_[tid] & 0xffffffffULL);
        ai_[tid] = (int)kf;
        out[1 + NDTOT + n0 + tid] = (float)kf;
    }
    __syncthreads();

    // ---- quantized output (NCHW) + loss ----
    const int h = tid >> 7, p = tid & 127;
    const int idx = ai_[p];
    const float4* erow = (const float4*)(emb + idx * D_) + h * 8;
    const float* xcol = xg + p;
    float* ob = out + 1 + b * (D_ * HW_) + hw0 + p;
    float local = 0.f;
#pragma unroll
    for (int j = 0; j < 8; ++j) {
        float4 e4 = erow[j];
        int d0 = h * 32 + j * 4;
        float ev[4] = {e4.x, e4.y, e4.z, e4.w};
#pragma unroll
        for (int cc = 0; cc < 4; ++cc) {
            float xv = xcol[(d0 + cc) * HW_];
            float df = ev[cc] - xv;
            local = fmaf(df, df, local);
            ob[(d0 + cc) * HW_] = ev[cc];
        }
    }
#pragma unroll
    for (int off = 32; off > 0; off >>= 1)
        local += __shfl_down(local, off, 64);
    if ((tid & 63) == 0) partial[tid >> 6] = local;
    __syncthreads();
    if (tid == 0) {
        float t = partial[0] + partial[1] + partial[2] + partial[3];
        atomicAdd(out, t * (1.25f / (float)NDTOT));   // loss = 1.25*mean((q-x)^2)
    }
}

extern "C" void kernel_launch(void* const* d_in, const int* in_sizes, int n_in,
                              void* d_out, int out_size, void* d_ws, size_t ws_size,
                              hipStream_t stream) {
    const float* inp = (const float*)d_in[0];
    const float* emb = (const float*)d_in[1];
    float* out = (float*)d_out;

    vq_prep_norm<<<2, 256, 0, stream>>>(emb, out);
    vq_prep_frag<<<32, 256, 0, stream>>>(emb);
    vq_main_kernel<<<N_ / 128, 256, 0, stream>>>(inp, emb, out);
}